// Round 5
// baseline (1251.638 us; speedup 1.0000x reference)
//
#include <hip/hip_runtime.h>
#include <math.h>

// Problem constants
#define B_    4096
#define T_    25
#define KENS  8
#define OBS   64
#define ACT   16
#define HID   512
#define OUTD  129
#define OUTP  144   // OUTD padded to 9 n-tiles of 16
#define INP   96    // 80 (obs+act) padded to 3 k-chunks of 32

// Tiling
#define M_    32    // rows per workgroup tile (2 MFMA m-tiles)
#define BLK   512   // 8 waves
#define NT1   32    // 512/16 n-tiles, layer1
#define KC1   3     // 96/32 k-chunks
#define NT2   32
#define KC2   16    // 512/32
#define NT3   9     // 144/16
#define KC3   16
#define XSTR  104   // X row stride in ushort (96 + 8 pad), 16B-aligned rows
#define HSTR  520   // h row stride in ushort (512 + 8 pad)
#define OSTR  148   // out_buf fp32 row stride
#define NSLOTS 1024 // 8 members * up to 128 tiles (worst-case skew)

typedef __bf16          bf16x8 __attribute__((ext_vector_type(8)));
typedef float           f32x4  __attribute__((ext_vector_type(4)));
typedef unsigned short  u16x8  __attribute__((ext_vector_type(8)));
typedef unsigned short  u16x4  __attribute__((ext_vector_type(4)));

static __device__ __forceinline__ unsigned short f2bf(float f) {
  unsigned int u = __builtin_bit_cast(unsigned int, f);
  u += 0x7FFFu + ((u >> 16) & 1u);   // RNE (values finite)
  return (unsigned short)(u >> 16);
}
static __device__ __forceinline__ float softplusf(float x) {
  return (x > 15.f) ? x : log1pf(__expf(x));
}

// ---------------------------------------------------------------------------
// Kernel 1: bucket rows by ensemble member, build tile descriptors.
// Handles assignments as int32 OR raw int64 (auto-detect odd words).
// slot = tile_i * 8 + k  => member k's tiles land on XCD k (blockIdx % 8).
// ---------------------------------------------------------------------------
__global__ void bucket_kernel(const int* __restrict__ assign,
                              int* __restrict__ rows_sorted,
                              int* __restrict__ desc) {
  __shared__ int cnt[KENS], base_[KENS], cur[KENS], odd_any;
  int tid = threadIdx.x;  // 256 threads
  if (tid < KENS) cnt[tid] = 0;
  if (tid == 0) odd_any = 0;
  __syncthreads();
  int o = 0;
  for (int i = tid; i < B_ / 2; i += 256) o |= assign[2 * i + 1];
  if (o) atomicOr(&odd_any, 1);
  __syncthreads();
  const int stride = (odd_any == 0) ? 2 : 1;   // int64 -> read low words
  for (int b = tid; b < B_; b += 256) atomicAdd(&cnt[assign[b * stride] & 7], 1);
  __syncthreads();
  if (tid == 0) {
    int off = 0;
    for (int k = 0; k < KENS; ++k) { base_[k] = off; cur[k] = off; off += cnt[k]; }
  }
  __syncthreads();
  for (int b = tid; b < B_; b += 256) {
    int k = assign[b * stride] & 7;
    int p = atomicAdd(&cur[k], 1);
    rows_sorted[p] = b;
  }
  for (int s = tid; s < NSLOTS; s += 256) {
    desc[s*4+0] = 0; desc[s*4+1] = 0; desc[s*4+2] = 0; desc[s*4+3] = 0;
  }
  __syncthreads();
  if (tid < KENS) {
    int k = tid, c = cnt[k], bs = base_[k];
    int ntile = (c + M_ - 1) / M_;
    for (int i = 0; i < ntile; ++i) {
      int s = i * KENS + k;
      int rem = c - i * M_;
      desc[s*4+0] = k;
      desc[s*4+1] = bs + i * M_;
      desc[s*4+2] = (rem < M_) ? rem : M_;
    }
  }
}

// ---------------------------------------------------------------------------
// Kernel 2: pre-pack fp32 weights into bf16 MFMA-B-fragment order.
// Packed chunk (c,nt): 64 lanes x 16B; lane holds W[c*32+(lane>>4)*8+j][nt*16+(lane&15)],
// j=0..7, zero-padded beyond logical K/N. 1 block (64 thr) per chunk.
// ---------------------------------------------------------------------------
__global__ void prepack_kernel(const float* __restrict__ w1,
                               const float* __restrict__ w2,
                               const float* __restrict__ w3,
                               unsigned short* __restrict__ w1p,
                               unsigned short* __restrict__ w2p,
                               unsigned short* __restrict__ w3p) {
  int cidx = blockIdx.x;
  int lane = threadIdx.x;  // 64
  const float* src;
  unsigned short* dst;
  int Klog, Nlog, c, nt;
  if (cidx < 8 * KC1 * NT1) {                 // 768 W1 chunks
    int k = cidx / (KC1 * NT1), r = cidx % (KC1 * NT1);
    c = r / NT1; nt = r % NT1;
    Klog = 80; Nlog = 512;
    src = w1 + (size_t)k * 80 * 512;
    dst = w1p + (size_t)cidx * 512;
  } else if (cidx < 8 * KC1 * NT1 + 8 * KC2 * NT2) {  // 4096 W2 chunks
    int q = cidx - 8 * KC1 * NT1;
    int k = q / (KC2 * NT2), r = q % (KC2 * NT2);
    c = r / NT2; nt = r % NT2;
    Klog = 512; Nlog = 512;
    src = w2 + (size_t)k * 512 * 512;
    dst = w2p + (size_t)q * 512;
  } else {                                    // 1152 W3 chunks
    int q = cidx - 8 * KC1 * NT1 - 8 * KC2 * NT2;
    int k = q / (KC3 * NT3), r = q % (KC3 * NT3);
    c = r / NT3; nt = r % NT3;
    Klog = 512; Nlog = 129;
    src = w3 + (size_t)k * 512 * 129;
    dst = w3p + (size_t)q * 512;
  }
  int kkb = c * 32 + (lane >> 4) * 8;
  int n   = nt * 16 + (lane & 15);
  u16x8 v;
  #pragma unroll
  for (int j = 0; j < 8; ++j) {
    int kk = kkb + j;
    float f = (kk < Klog && n < Nlog) ? src[(size_t)kk * Nlog + n] : 0.f;
    v[j] = f2bf(f);
  }
  *reinterpret_cast<u16x8*>(dst + (size_t)lane * 8) = v;
}

// ---------------------------------------------------------------------------
// Kernel 3: persistent rollout. One 32-row tile of one member, all 25 steps.
// Only the ASSIGNED member's MLP is computed (8x FLOP reduction vs reference).
// Outputs are FLOAT32 (reference output dtype).
// ---------------------------------------------------------------------------
__global__ __launch_bounds__(BLK, 2) void rollout_kernel(
    const float* __restrict__ obs,
    const float* __restrict__ act,
    const float* __restrict__ b1g,
    const float* __restrict__ b2g,
    const float* __restrict__ b3g,
    const float* __restrict__ mlvg,
    const float* __restrict__ mnvg,
    const float* __restrict__ noiseg,
    const int* __restrict__ desc,
    const int* __restrict__ rows_sorted,
    const unsigned short* __restrict__ w1p,
    const unsigned short* __restrict__ w2p,
    const unsigned short* __restrict__ w3p,
    float* __restrict__ out_obs,
    float* __restrict__ out_rew) {
  const int slot  = blockIdx.x;
  const int k     = desc[slot*4+0];
  const int start = desc[slot*4+1];
  const int nrows = desc[slot*4+2];
  if (nrows == 0) return;   // uniform early exit, before any barrier

  __shared__ unsigned short Xs[M_ * XSTR];
  __shared__ unsigned short H1[M_ * HSTR];
  __shared__ unsigned short H2[M_ * HSTR];
  __shared__ float          OB[M_ * OSTR];
  __shared__ float          NZf[M_ * OBS];
  __shared__ float B1s[HID], B2s[HID], B3s[OUTP];
  __shared__ float MLV[OBS], MNV[OBS];
  __shared__ int   RID[M_];

  const int tid  = threadIdx.x;
  const int lane = tid & 63;
  const int wave = tid >> 6;       // 0..7
  const int quad = lane >> 4;      // 0..3
  const int l15  = lane & 15;

  if (tid < M_)
    RID[tid] = rows_sorted[start + ((tid < nrows) ? tid : 0)];
  __syncthreads();

  // biases / logvar bounds -> LDS (fp32 inputs, direct)
  for (int i = tid; i < HID; i += BLK) {
    B1s[i] = b1g[k * HID + i];
    B2s[i] = b2g[k * HID + i];
  }
  for (int i = tid; i < OUTP; i += BLK)
    B3s[i] = (i < OUTD) ? b3g[k * OUTD + i] : 0.f;
  if (tid < OBS) { MLV[tid] = mlvg[tid]; MNV[tid] = mnvg[tid]; }

  // X init: obs cols 0..63 (fp32 -> bf16); 32 rows x 16 threads x 4 elems
  {
    int row = tid >> 4, e = (tid & 15) * 4;
    int rid = RID[row];
    f32x4 v = *reinterpret_cast<const f32x4*>(obs + (size_t)rid * OBS + e);
    u16x4 ov;
    #pragma unroll
    for (int j = 0; j < 4; ++j) ov[j] = f2bf(v[j]);
    *reinterpret_cast<u16x4*>(&Xs[row * XSTR + e]) = ov;
  }
  // zero pad cols 80..103 (stays zero; GEMM K covers up to 95)
  for (int i = tid; i < M_ * 24; i += BLK) {
    int row = i / 24, cc = 80 + i % 24;
    Xs[row * XSTR + cc] = 0;
  }

  const u16x8* W1B = reinterpret_cast<const u16x8*>(w1p) + (size_t)k * KC1 * NT1 * 64;
  const u16x8* W2B = reinterpret_cast<const u16x8*>(w2p) + (size_t)k * KC2 * NT2 * 64;
  const u16x8* W3B = reinterpret_cast<const u16x8*>(w3p) + (size_t)k * KC3 * NT3 * 64;

  for (int t = 0; t < T_; ++t) {
    // ---- phase 1: stage act (X cols 64..79, fp32->bf16) and noise (fp32) ----
    {
      int row = tid >> 4, e = tid & 15;
      int rid = RID[row];
      Xs[row * XSTR + OBS + e] = f2bf(act[((size_t)rid * T_ + t) * ACT + e]);
    }
    {
      int row = tid >> 4, e = (tid & 15) * 4;
      int rid = RID[row];
      *reinterpret_cast<f32x4*>(&NZf[row * OBS + e]) =
          *reinterpret_cast<const f32x4*>(
              noiseg + (((size_t)t * KENS + k) * B_ + rid) * OBS + e);
    }
    __syncthreads();

    // ---- layer 1: X(32x96) @ W1(96x512), swish -> H1 ----
    {
      f32x4 acc[2][4];
      #pragma unroll
      for (int mt = 0; mt < 2; ++mt)
        #pragma unroll
        for (int j = 0; j < 4; ++j) acc[mt][j] = (f32x4){0.f, 0.f, 0.f, 0.f};
      const int nt0 = wave * 4;
      #pragma unroll
      for (int c = 0; c < KC1; ++c) {
        bf16x8 a0 = *reinterpret_cast<const bf16x8*>(&Xs[l15 * XSTR + c * 32 + quad * 8]);
        bf16x8 a1 = *reinterpret_cast<const bf16x8*>(&Xs[(16 + l15) * XSTR + c * 32 + quad * 8]);
        #pragma unroll
        for (int j = 0; j < 4; ++j) {
          bf16x8 bb = __builtin_bit_cast(bf16x8, W1B[(c * NT1 + nt0 + j) * 64 + lane]);
          acc[0][j] = __builtin_amdgcn_mfma_f32_16x16x32_bf16(a0, bb, acc[0][j], 0, 0, 0);
          acc[1][j] = __builtin_amdgcn_mfma_f32_16x16x32_bf16(a1, bb, acc[1][j], 0, 0, 0);
        }
      }
      #pragma unroll
      for (int j = 0; j < 4; ++j) {
        int col = (nt0 + j) * 16 + l15;
        float bias = B1s[col];
        #pragma unroll
        for (int mt = 0; mt < 2; ++mt)
          #pragma unroll
          for (int r = 0; r < 4; ++r) {
            int row = mt * 16 + quad * 4 + r;
            float v = acc[mt][j][r] + bias;
            H1[row * HSTR + col] = f2bf(v / (1.f + __expf(-v)));
          }
      }
    }
    __syncthreads();

    // ---- layer 2: H1(32x512) @ W2(512x512), swish -> H2 ----
    {
      f32x4 acc[2][4];
      #pragma unroll
      for (int mt = 0; mt < 2; ++mt)
        #pragma unroll
        for (int j = 0; j < 4; ++j) acc[mt][j] = (f32x4){0.f, 0.f, 0.f, 0.f};
      const int nt0 = wave * 4;
      #pragma unroll
      for (int c = 0; c < KC2; ++c) {
        bf16x8 a0 = *reinterpret_cast<const bf16x8*>(&H1[l15 * HSTR + c * 32 + quad * 8]);
        bf16x8 a1 = *reinterpret_cast<const bf16x8*>(&H1[(16 + l15) * HSTR + c * 32 + quad * 8]);
        #pragma unroll
        for (int j = 0; j < 4; ++j) {
          bf16x8 bb = __builtin_bit_cast(bf16x8, W2B[(c * NT2 + nt0 + j) * 64 + lane]);
          acc[0][j] = __builtin_amdgcn_mfma_f32_16x16x32_bf16(a0, bb, acc[0][j], 0, 0, 0);
          acc[1][j] = __builtin_amdgcn_mfma_f32_16x16x32_bf16(a1, bb, acc[1][j], 0, 0, 0);
        }
      }
      #pragma unroll
      for (int j = 0; j < 4; ++j) {
        int col = (nt0 + j) * 16 + l15;
        float bias = B2s[col];
        #pragma unroll
        for (int mt = 0; mt < 2; ++mt)
          #pragma unroll
          for (int r = 0; r < 4; ++r) {
            int row = mt * 16 + quad * 4 + r;
            float v = acc[mt][j][r] + bias;
            H2[row * HSTR + col] = f2bf(v / (1.f + __expf(-v)));
          }
      }
    }
    __syncthreads();

    // ---- layer 3: H2(32x512) @ W3(512x144) + b3 -> OB (fp32) ----
    {
      f32x4 accA[2], accB[2];
      #pragma unroll
      for (int mt = 0; mt < 2; ++mt) {
        accA[mt] = (f32x4){0.f, 0.f, 0.f, 0.f};
        accB[mt] = (f32x4){0.f, 0.f, 0.f, 0.f};
      }
      const int ntA = wave;
      const bool hasB = (wave == 0);   // wave 0 also takes n-tile 8 (cols 128..143)
      #pragma unroll
      for (int c = 0; c < KC3; ++c) {
        bf16x8 a0 = *reinterpret_cast<const bf16x8*>(&H2[l15 * HSTR + c * 32 + quad * 8]);
        bf16x8 a1 = *reinterpret_cast<const bf16x8*>(&H2[(16 + l15) * HSTR + c * 32 + quad * 8]);
        bf16x8 bA = __builtin_bit_cast(bf16x8, W3B[(c * NT3 + ntA) * 64 + lane]);
        accA[0] = __builtin_amdgcn_mfma_f32_16x16x32_bf16(a0, bA, accA[0], 0, 0, 0);
        accA[1] = __builtin_amdgcn_mfma_f32_16x16x32_bf16(a1, bA, accA[1], 0, 0, 0);
        if (hasB) {
          bf16x8 bB = __builtin_bit_cast(bf16x8, W3B[(c * NT3 + 8) * 64 + lane]);
          accB[0] = __builtin_amdgcn_mfma_f32_16x16x32_bf16(a0, bB, accB[0], 0, 0, 0);
          accB[1] = __builtin_amdgcn_mfma_f32_16x16x32_bf16(a1, bB, accB[1], 0, 0, 0);
        }
      }
      {
        int col = ntA * 16 + l15;
        float bias = B3s[col];
        #pragma unroll
        for (int mt = 0; mt < 2; ++mt)
          #pragma unroll
          for (int r = 0; r < 4; ++r)
            OB[(mt * 16 + quad * 4 + r) * OSTR + col] = accA[mt][r] + bias;
      }
      if (hasB) {
        int col = 128 + l15;
        float bias = B3s[col];
        #pragma unroll
        for (int mt = 0; mt < 2; ++mt)
          #pragma unroll
          for (int r = 0; r < 4; ++r)
            OB[(mt * 16 + quad * 4 + r) * OSTR + col] = accB[mt][r] + bias;
      }
    }
    __syncthreads();

    // ---- postprocess: logvar soft-clamp, sample, fp32 outputs + next X ----
    #pragma unroll
    for (int it = 0; it < (M_ * OBS) / BLK; ++it) {   // 4 iters
      int idx = it * BLK + tid;
      int row = idx >> 6, d = idx & 63;
      float mean = OB[row * OSTR + d];
      float lv   = OB[row * OSTR + OBS + d];
      float a = MLV[d], b = MNV[d];
      lv = a - softplusf(a - lv);
      lv = b + softplusf(lv - b);
      float nobs = mean + NZf[row * OBS + d] * __expf(0.5f * lv);
      Xs[row * XSTR + d] = f2bf(nobs);                // next step's input (bf16)
      if (row < nrows)
        out_obs[((size_t)RID[row] * T_ + t) * OBS + d] = nobs;   // fp32 output
    }
    if (tid < M_ && tid < nrows)
      out_rew[(size_t)RID[tid] * T_ + t] = OB[tid * OSTR + 128]; // fp32 output
    __syncthreads();   // protect Xs/NZf against next iteration's phase 1
  }
}

// ---------------------------------------------------------------------------
extern "C" void kernel_launch(void* const* d_in, const int* in_sizes, int n_in,
                              void* d_out, int out_size, void* d_ws, size_t ws_size,
                              hipStream_t stream) {
  const float* obs   = (const float*)d_in[0];
  const float* act   = (const float*)d_in[1];
  const float* W1    = (const float*)d_in[2];
  const float* b1    = (const float*)d_in[3];
  const float* W2    = (const float*)d_in[4];
  const float* b2    = (const float*)d_in[5];
  const float* W3    = (const float*)d_in[6];
  const float* b3    = (const float*)d_in[7];
  const float* mlv   = (const float*)d_in[8];
  const float* mnv   = (const float*)d_in[9];
  const float* noise = (const float*)d_in[10];
  const int*   assign= (const int*)d_in[11];
  float* out = (float*)d_out;   // reference output dtype: float32

  char* ws = (char*)d_ws;
  int*            rows_sorted = (int*)(ws + 0);                 // 16 KB
  int*            desc        = (int*)(ws + 16384);             // 16 KB
  unsigned short* w1p         = (unsigned short*)(ws + 32768);  // 768 KB
  unsigned short* w2p         = (unsigned short*)(ws + 819200); // 4 MB
  unsigned short* w3p         = (unsigned short*)(ws + 5013504);// 1.125 MB -> total ~6.2 MB

  bucket_kernel<<<1, 256, 0, stream>>>(assign, rows_sorted, desc);
  prepack_kernel<<<8 * (KC1 * NT1 + KC2 * NT2 + KC3 * NT3), 64, 0, stream>>>(
      W1, W2, W3, w1p, w2p, w3p);
  rollout_kernel<<<NSLOTS, BLK, 0, stream>>>(
      obs, act, b1, b2, b3, mlv, mnv, noise, desc, rows_sorted,
      w1p, w2p, w3p, out, out + (size_t)B_ * T_ * OBS);
}